// Round 7
// baseline (276.719 us; speedup 1.0000x reference)
//
#include <hip/hip_runtime.h>
#include <hip/hip_bf16.h>
#include <stdint.h>

#define T_STEPS 512
#define BATCH 64
#define CH 512

using short8 = __attribute__((ext_vector_type(8))) short;
using f32x4  = __attribute__((ext_vector_type(4))) float;

__device__ __forceinline__ unsigned short f2b(float f) {
    union { __hip_bfloat16 h; unsigned short u; } c;
    c.h = __float2bfloat16(f);
    return c.u;
}
__device__ __forceinline__ float b2f(unsigned short h) {
    union { unsigned u; float f; } c; c.u = ((unsigned)h) << 16;
    return c.f;
}

// ---------------- prep ----------------
__global__ void prep(const float* __restrict__ cw, const float* __restrict__ cb,
                     const float* __restrict__ gamma, const float* __restrict__ beta,
                     const float* __restrict__ mean, const float* __restrict__ var,
                     unsigned short* __restrict__ wb,   // [d][c] bf16, pre-scaled 0.04*is_d
                     float* __restrict__ wt,            // [c][d] fp32 raw w1
                     float* __restrict__ isb,
                     float* __restrict__ k0p,           // B0_d
                     int* __restrict__ flag) {
    int idx = blockIdx.x * 256 + threadIdx.x;
    if (idx == 0) *flag = 0x7fffffff;
    if (idx >= CH * CH) return;
    int d = idx >> 9, c = idx & 511;
    float is = gamma[d] * rsqrtf(var[d] + 1e-5f);
    float w = cw[((size_t)d * CH + c) * 3 + 1];
    wb[idx] = f2b(0.04f * is * w);
    wt[(size_t)c * CH + d] = w;
    if (c == 0) {
        isb[d] = is;
        k0p[d] = 0.1f * ((cb[d] - mean[d]) * is + beta[d]);
    }
}

// ---------------- fused GEMM: BM=128, BN=512(full), BK=32, 1 barrier/k-step ----------------
#define GBM 128
#define PADK 40   // 80B rows: 16B-aligned; fragment reads 2-way banked (free, m136)

__global__ __launch_bounds__(512, 2) void gemm_fused(
    const float* __restrict__ Xp,
    const unsigned short* __restrict__ wbp,
    const float* __restrict__ k0p,
    unsigned short* __restrict__ Wbuf,     // [Mc][512] bf16
    float* __restrict__ outp,
    int Mc)
{
    __shared__ __align__(16) unsigned short As[2][GBM][PADK];
    __shared__ __align__(16) unsigned short Bs[2][512][PADK];
    int tid = threadIdx.x;
    int lane = tid & 63, wid = tid >> 6;
    int wm = wid >> 2, wn = wid & 3;       // 2x4 waves, 64x128 tile each
    int i0 = blockIdx.x * GBM;
    int fm = lane & 15, fq = lane >> 4;
    int kq = fq * 8;

    // staging maps
    int ar = tid >> 2;                 // A row 0..127 (also B row base)
    int ak = (tid & 3) * 8;            // k-offset: 0,8,16,24

    int grow = i0 + ar;
    bool arv = grow < Mc;
    int growc = arv ? grow : (Mc - 1);
    const float* xrow = &Xp[(size_t)growc * CH + ak];
    float* orow = &outp[(size_t)grow * CH + ak];
    const unsigned short* brow = &wbp[(size_t)ar * CH + ak];

    f32x4 acc[4][8] = {};

    // staging registers (one chunk in flight)
    float4 sa0, sa1;
    short8 sb[4];

    // ---- prologue: chunk 0 -> buf0, out-store chunk 0 ----
    {
        sa0 = *(const float4*)&xrow[0];
        sa1 = *(const float4*)&xrow[4];
        #pragma unroll
        for (int p = 0; p < 4; ++p)
            sb[p] = *(const short8*)&brow[(size_t)p * 128 * CH];
        short8 av;
        av[0]=f2b(sa0.x); av[1]=f2b(sa0.y); av[2]=f2b(sa0.z); av[3]=f2b(sa0.w);
        av[4]=f2b(sa1.x); av[5]=f2b(sa1.y); av[6]=f2b(sa1.z); av[7]=f2b(sa1.w);
        *(short8*)&As[0][ar][ak] = av;
        #pragma unroll
        for (int p = 0; p < 4; ++p)
            *(short8*)&Bs[0][ar + p * 128][ak] = sb[p];
        if (arv) {
            *(float4*)&orow[0] = make_float4(0.4f*sa0.x, 0.4f*sa0.y, 0.4f*sa0.z, 0.4f*sa0.w);
            *(float4*)&orow[4] = make_float4(0.4f*sa1.x, 0.4f*sa1.y, 0.4f*sa1.z, 0.4f*sa1.w);
        }
    }
    __syncthreads();

    for (int ks = 0; ks < 16; ++ks) {
        int cur = ks & 1;
        int kn = (ks + 1) * 32;
        // (1) issue next chunk's global loads early
        if (kn < 512) {
            sa0 = *(const float4*)&xrow[kn];
            sa1 = *(const float4*)&xrow[kn + 4];
            #pragma unroll
            for (int p = 0; p < 4; ++p)
                sb[p] = *(const short8*)&brow[(size_t)p * 128 * CH + kn];
        }
        // (2) fragment reads + MFMA on current buffer
        short8 af[4], bfr[8];
        #pragma unroll
        for (int i = 0; i < 4; ++i)
            af[i] = *(const short8*)&As[cur][wm * 64 + i * 16 + fm][kq];
        #pragma unroll
        for (int j = 0; j < 8; ++j)
            bfr[j] = *(const short8*)&Bs[cur][wn * 128 + j * 16 + fm][kq];
        #pragma unroll
        for (int i = 0; i < 4; ++i)
            #pragma unroll
            for (int j = 0; j < 8; ++j)
                acc[i][j] = __builtin_amdgcn_mfma_f32_16x16x32_bf16(af[i], bfr[j], acc[i][j], 0, 0, 0);
        // (3) stage next chunk into the other buffer + fused out-store
        if (kn < 512) {
            short8 av;
            av[0]=f2b(sa0.x); av[1]=f2b(sa0.y); av[2]=f2b(sa0.z); av[3]=f2b(sa0.w);
            av[4]=f2b(sa1.x); av[5]=f2b(sa1.y); av[6]=f2b(sa1.z); av[7]=f2b(sa1.w);
            *(short8*)&As[cur ^ 1][ar][ak] = av;
            #pragma unroll
            for (int p = 0; p < 4; ++p)
                *(short8*)&Bs[cur ^ 1][ar + p * 128][ak] = sb[p];
            if (arv) {
                *(float4*)&orow[kn]     = make_float4(0.4f*sa0.x, 0.4f*sa0.y, 0.4f*sa0.z, 0.4f*sa0.w);
                *(float4*)&orow[kn + 4] = make_float4(0.4f*sa1.x, 0.4f*sa1.y, 0.4f*sa1.z, 0.4f*sa1.w);
            }
        }
        __syncthreads();
    }

    // epilogue: Wbuf = acc + B0 (bf16)
    float b0e[8];
    #pragma unroll
    for (int j = 0; j < 8; ++j) b0e[j] = k0p[wn * 128 + j * 16 + fm];
    #pragma unroll
    for (int i = 0; i < 4; ++i)
        #pragma unroll
        for (int r = 0; r < 4; ++r) {
            int row = i0 + wm * 64 + i * 16 + fq * 4 + r;
            if (row < Mc) {
                #pragma unroll
                for (int j = 0; j < 8; ++j) {
                    int col = wn * 128 + j * 16 + fm;
                    Wbuf[(size_t)row * CH + col] = f2b(acc[i][j][r] + b0e[j]);
                }
            }
        }
}

// ---------------- single-read speculative scan: segsum+pmax, prefix, bound ----------------
__device__ __forceinline__ short8 wload(const unsigned short* Wbuf, int t, int a0, int b, int c0) {
    int r = t - 1 - a0; if (r < 0) r = 0;
    return *(const short8*)&Wbuf[((size_t)r * BATCH + b) * CH + c0];
}

__global__ __launch_bounds__(512) void scan_all(
    const unsigned short* __restrict__ Wbuf,
    const float* __restrict__ k0p,
    const float* __restrict__ vcin,
    float* __restrict__ vcout,
    int* __restrict__ flag,
    int t0, int a0, int segs, int chunk_idx)
{
    const float F = 1.1790184577738595e-3f;   // 0.9^64
    __shared__ float Ssh[8][CH];
    int b = blockIdx.x;
    int seg = threadIdx.x >> 6;
    int lane = threadIdx.x & 63;
    int c0 = lane * 8;
    bool active = seg < segs;
    int tstart = t0 + seg * 64;

    float B0[8];
    #pragma unroll
    for (int k = 0; k < 8; ++k) B0[k] = k0p[c0 + k];

    // ---- pass A (single Wbuf read): S = zero-start end value, P = zero-start max ----
    float S[8] = {};
    float P[8];
    #pragma unroll
    for (int k = 0; k < 8; ++k) P[k] = -1e30f;
    if (active) {
        short8 pz[4];
        #pragma unroll
        for (int p = 0; p < 4; ++p) pz[p] = wload(Wbuf, tstart + p, a0, b, c0);
        for (int ii = 0; ii < 64; ii += 4) {
            #pragma unroll
            for (int p = 0; p < 4; ++p) {
                int t = tstart + ii + p;
                short8 zv = pz[p];
                int tn = ii + p + 4;
                if (tn < 64) pz[p] = wload(Wbuf, tstart + tn, a0, b, c0);
                #pragma unroll
                for (int k = 0; k < 8; ++k) {
                    float wv = (t == 0) ? B0[k] : b2f((unsigned short)zv[k]);
                    S[k] = fmaf(0.9f, S[k], wv);
                    P[k] = fmaxf(P[k], S[k]);
                }
            }
        }
        #pragma unroll
        for (int k = 0; k < 8; ++k) Ssh[seg][c0 + k] = S[k];
    }
    __syncthreads();

    // ---- prefix: exact v at my segment start ----
    float v[8];
    if (t0 == 0) {
        #pragma unroll
        for (int k = 0; k < 8; ++k) v[k] = 0.0f;
    } else {
        const float* vp = &vcin[(size_t)b * CH + c0];
        float4 v0 = *(const float4*)&vp[0], v1 = *(const float4*)&vp[4];
        v[0]=v0.x; v[1]=v0.y; v[2]=v0.z; v[3]=v0.w; v[4]=v1.x; v[5]=v1.y; v[6]=v1.z; v[7]=v1.w;
    }
    for (int u = 0; u < seg; ++u) {
        #pragma unroll
        for (int k = 0; k < 8; ++k) v[k] = fmaf(v[k], F, Ssh[u][c0 + k]);
    }

    // ---- bound check: max_t v_t <= P + 0.9*max(v_start,0)  (exact upper bound) ----
    if (active) {
        bool hit = false;
        #pragma unroll
        for (int k = 0; k < 8; ++k)
            hit |= (fmaf(0.9f, fmaxf(v[k], 0.0f), P[k]) >= 0.995f);
        if (__ballot(hit) != 0ULL && lane == 0) atomicMin(flag, chunk_idx);
        if (seg == segs - 1) {
            float* vp = &vcout[(size_t)b * CH + c0];
            float ve[8];
            #pragma unroll
            for (int k = 0; k < 8; ++k) ve[k] = fmaf(v[k], F, S[k]);
            *(float4*)&vp[0] = make_float4(ve[0], ve[1], ve[2], ve[3]);
            *(float4*)&vp[4] = make_float4(ve[4], ve[5], ve[6], ve[7]);
        }
    }
}

// ---------------- exact sequential fallback (runs only if flag fired) ----------------
__global__ __launch_bounds__(64) void seq_fix(
    const float* __restrict__ x,
    const float* __restrict__ wt,
    const unsigned short* __restrict__ Wbuf,
    const float* __restrict__ isb,
    const float* __restrict__ k0p,
    const int* __restrict__ flag,
    const float* __restrict__ vcin,
    float* __restrict__ out,
    float* __restrict__ v_state,
    unsigned long long* __restrict__ s_state,
    int t0, int t1, int a0, int chunk_idx, int save_state)
{
    int fl = *flag;
    if (fl > chunk_idx) return;
    int b = blockIdx.x;
    int lane = threadIdx.x;
    int c0 = lane * 8;

    float is6[8], B0[8];
    #pragma unroll
    for (int k = 0; k < 8; ++k) {
        is6[k] = 0.06f * isb[c0 + k];
        B0[k]  = k0p[c0 + k];
    }

    float v[8];
    unsigned long long mk[8];
    if (t0 == 0) {
        #pragma unroll
        for (int k = 0; k < 8; ++k) v[k] = 0.0f;
        #pragma unroll
        for (int j = 0; j < 8; ++j) mk[j] = 0ULL;
    } else if (fl == chunk_idx) {
        #pragma unroll
        for (int k = 0; k < 8; ++k) v[k] = vcin[(size_t)b * CH + c0 + k];
        #pragma unroll
        for (int j = 0; j < 8; ++j) mk[j] = 0ULL;
    } else {
        #pragma unroll
        for (int k = 0; k < 8; ++k) v[k] = v_state[(size_t)b * CH + c0 + k];
        #pragma unroll
        for (int j = 0; j < 8; ++j) mk[j] = s_state[b * 8 + j];
    }

    float xc[8]; short8 wc;
    {
        const float4* xp = (const float4*)&x[((size_t)t0 * BATCH + b) * CH + c0];
        float4 x0 = xp[0], x1 = xp[1];
        xc[0]=x0.x; xc[1]=x0.y; xc[2]=x0.z; xc[3]=x0.w; xc[4]=x1.x; xc[5]=x1.y; xc[6]=x1.z; xc[7]=x1.w;
        wc = wload(Wbuf, t0, a0, b, c0);
    }
    for (int t = t0; t < t1; ++t) {
        float xn[8]; short8 wn_;
        if (t + 1 < t1) {
            const float4* xp = (const float4*)&x[((size_t)(t + 1) * BATCH + b) * CH + c0];
            float4 x0 = xp[0], x1 = xp[1];
            xn[0]=x0.x; xn[1]=x0.y; xn[2]=x0.z; xn[3]=x0.w; xn[4]=x1.x; xn[5]=x1.y; xn[6]=x1.z; xn[7]=x1.w;
            wn_ = wload(Wbuf, t + 1, a0, b, c0);
        }
        float acc[8] = {};
        unsigned long long anym = mk[0]|mk[1]|mk[2]|mk[3]|mk[4]|mk[5]|mk[6]|mk[7];
        if (anym) {
            #pragma unroll
            for (int j = 0; j < 8; ++j) {
                unsigned long long m = mk[j];
                while (m) {
                    int l = __builtin_ctzll(m); m &= m - 1;
                    const float4* wr = (const float4*)&wt[(size_t)(l * 8 + j) * CH + c0];
                    float4 w0 = wr[0], w1 = wr[1];
                    acc[0]+=w0.x; acc[1]+=w0.y; acc[2]+=w0.z; acc[3]+=w0.w;
                    acc[4]+=w1.x; acc[5]+=w1.y; acc[6]+=w1.z; acc[7]+=w1.w;
                }
            }
        }
        bool s[8];
        #pragma unroll
        for (int k = 0; k < 8; ++k) {
            float wv = (t == 0) ? B0[k] : b2f((unsigned short)wc[k]);
            float vv = fmaf(0.9f, v[k], fmaf(is6[k], acc[k], wv));
            s[k] = (vv >= 1.0f);
            v[k] = s[k] ? 0.0f : vv;
        }
        float4* op = (float4*)&out[((size_t)t * BATCH + b) * CH + c0];
        op[0] = make_float4(fmaf(0.4f,xc[0],s[0]?0.6f:0.f), fmaf(0.4f,xc[1],s[1]?0.6f:0.f),
                            fmaf(0.4f,xc[2],s[2]?0.6f:0.f), fmaf(0.4f,xc[3],s[3]?0.6f:0.f));
        op[1] = make_float4(fmaf(0.4f,xc[4],s[4]?0.6f:0.f), fmaf(0.4f,xc[5],s[5]?0.6f:0.f),
                            fmaf(0.4f,xc[6],s[6]?0.6f:0.f), fmaf(0.4f,xc[7],s[7]?0.6f:0.f));
        #pragma unroll
        for (int j = 0; j < 8; ++j) mk[j] = __ballot(s[j]);
        #pragma unroll
        for (int k = 0; k < 8; ++k) xc[k] = xn[k];
        wc = wn_;
    }
    if (save_state) {
        #pragma unroll
        for (int k = 0; k < 8; ++k) v_state[(size_t)b * CH + c0 + k] = v[k];
        if (lane < 8) s_state[b * 8 + lane] = mk[lane];
    }
}

extern "C" void kernel_launch(void* const* d_in, const int* in_sizes, int n_in,
                              void* d_out, int out_size, void* d_ws, size_t ws_size,
                              hipStream_t stream) {
    const float* x     = (const float*)d_in[0];
    const float* cw    = (const float*)d_in[1];
    const float* cb    = (const float*)d_in[2];
    const float* gamma = (const float*)d_in[3];
    const float* beta  = (const float*)d_in[4];
    const float* mean  = (const float*)d_in[5];
    const float* var   = (const float*)d_in[6];
    float* out = (float*)d_out;

    char* ws = (char*)d_ws;
    size_t off = 0;
    auto alloc = [&](size_t bytes) -> char* {
        char* p = ws + off;
        off = (off + bytes + 255) & ~(size_t)255;
        return p;
    };
    unsigned short* wb = (unsigned short*)alloc((size_t)CH * CH * 2);
    float* wt  = (float*)alloc((size_t)CH * CH * 4);
    float* isb = (float*)alloc(CH * 4);
    float* k0p = (float*)alloc(CH * 4);
    int* flag  = (int*)alloc(256);
    float* vst = (float*)alloc((size_t)BATCH * CH * 4);
    unsigned long long* sst = (unsigned long long*)alloc(BATCH * 8 * 8);
    float* vca = (float*)alloc((size_t)BATCH * CH * 4);
    float* vcb = (float*)alloc((size_t)BATCH * CH * 4);
    unsigned short* Wbuf = (unsigned short*)(ws + off);

    size_t avail = (ws_size > off) ? ws_size - off : 0;
    long rows = (long)(avail / ((size_t)BATCH * CH * 2));
    long cs = ((rows - 1) / 64) * 64;
    if (cs > T_STEPS) cs = T_STEPS;
    if (cs < 64) cs = 64;
    int CS = (int)cs;

    hipLaunchKernelGGL(prep, dim3((CH * CH + 255) / 256), dim3(256), 0, stream,
                       cw, cb, gamma, beta, mean, var, wb, wt, isb, k0p, flag);

    float *vin = vca, *vout = vcb;
    int k = 0;
    for (int t0 = 0; t0 < T_STEPS; t0 += CS, ++k) {
        int t1 = t0 + CS; if (t1 > T_STEPS) t1 = T_STEPS;
        int a0 = (t0 == 0) ? 0 : t0 - 1;
        int gend = (t1 == T_STEPS) ? T_STEPS : t1 - 1;
        int Mc = (gend - a0) * BATCH;
        hipLaunchKernelGGL(gemm_fused, dim3((Mc + GBM - 1) / GBM), dim3(512), 0, stream,
                           x + (size_t)a0 * BATCH * CH, wb, k0p, Wbuf,
                           out + (size_t)a0 * BATCH * CH, Mc);
        int segs = (t1 - t0) / 64;
        hipLaunchKernelGGL(scan_all, dim3(BATCH), dim3(512), 0, stream,
                           Wbuf, k0p, vin, vout, flag, t0, a0, segs, k);
        hipLaunchKernelGGL(seq_fix, dim3(BATCH), dim3(64), 0, stream,
                           x, wt, Wbuf, isb, k0p, flag, vin, out, vst, sst,
                           t0, t1, a0, k, (t1 < T_STEPS) ? 1 : 0);
        float* tmp = vin; vin = vout; vout = tmp;
    }
}

// Round 8
// 77.286 us; speedup vs baseline: 3.5805x; 3.5805x over previous
//
#include <hip/hip_runtime.h>
#include <hip/hip_bf16.h>
#include <stdint.h>

#define T_STEPS 512
#define BATCH 64
#define CH 512

using short8 = __attribute__((ext_vector_type(8))) short;
using f32x4  = __attribute__((ext_vector_type(4))) float;

__device__ __forceinline__ unsigned short f2b(float f) {
    union { __hip_bfloat16 h; unsigned short u; } c;
    c.h = __float2bfloat16(f);
    return c.u;
}
__device__ __forceinline__ float b2f(unsigned short h) {
    union { unsigned u; float f; } c; c.u = ((unsigned)h) << 16;
    return c.f;
}

// T4-style barrier: LDS-only ordering, NO vmcnt drain (stores/loads stay in flight)
#define LDS_BARRIER() do {                                   \
    __builtin_amdgcn_sched_barrier(0);                       \
    asm volatile("s_waitcnt lgkmcnt(0)" ::: "memory");       \
    __builtin_amdgcn_s_barrier();                            \
    __builtin_amdgcn_sched_barrier(0);                       \
} while (0)

// ---------------- prep ----------------
__global__ void prep(const float* __restrict__ cw, const float* __restrict__ cb,
                     const float* __restrict__ gamma, const float* __restrict__ beta,
                     const float* __restrict__ mean, const float* __restrict__ var,
                     unsigned short* __restrict__ wb,   // [d][c] bf16, pre-scaled 0.04*is_d
                     float* __restrict__ wt,            // [c][d] fp32 raw w1
                     float* __restrict__ isb,
                     float* __restrict__ k0p,           // B0_d
                     int* __restrict__ flag) {
    int idx = blockIdx.x * 256 + threadIdx.x;
    if (idx == 0) *flag = 0x7fffffff;
    if (idx >= CH * CH) return;
    int d = idx >> 9, c = idx & 511;
    float is = gamma[d] * rsqrtf(var[d] + 1e-5f);
    float w = cw[((size_t)d * CH + c) * 3 + 1];
    wb[idx] = f2b(0.04f * is * w);
    wt[(size_t)c * CH + d] = w;
    if (c == 0) {
        isb[d] = is;
        k0p[d] = 0.1f * ((cb[d] - mean[d]) * is + beta[d]);
    }
}

// ---------------- fused GEMM: BM=128, BN=512, BK=32, lgkm-only barriers ----------------
#define GBM 128
#define PADK 40   // 80B rows: frag ds_read_b128 2-way banked (free, m136)

__global__ __launch_bounds__(512, 2) void gemm_fused(
    const float* __restrict__ Xp,
    const unsigned short* __restrict__ wbp,
    const float* __restrict__ k0p,
    unsigned short* __restrict__ Wbuf,     // [Mc][512] bf16
    float* __restrict__ outp,
    int Mc)
{
    __shared__ __align__(16) unsigned short As[2][GBM][PADK];
    __shared__ __align__(16) unsigned short Bs[2][512][PADK];
    int tid = threadIdx.x;
    int lane = tid & 63, wid = tid >> 6;
    int wm = wid >> 2, wn = wid & 3;       // 2x4 waves, 64x128 tile each
    int i0 = blockIdx.x * GBM;
    int fm = lane & 15, fq = lane >> 4;
    int kq = fq * 8;

    int ar = tid >> 2;                 // A/B row 0..127
    int ak = (tid & 3) * 8;            // k-offset: 0,8,16,24

    int grow = i0 + ar;
    bool arv = grow < Mc;
    int growc = arv ? grow : (Mc - 1);
    const float* xrow = &Xp[(size_t)growc * CH + ak];
    float* orow = &outp[(size_t)grow * CH + ak];
    const unsigned short* brow = &wbp[(size_t)ar * CH + ak];

    f32x4 acc[4][8] = {};
    float4 sa0, sa1;
    short8 sb[4];

    // ---- prologue: chunk 0 -> buf0, fused out-store chunk 0 ----
    {
        sa0 = *(const float4*)&xrow[0];
        sa1 = *(const float4*)&xrow[4];
        #pragma unroll
        for (int p = 0; p < 4; ++p)
            sb[p] = *(const short8*)&brow[(size_t)p * 128 * CH];
        short8 av;
        av[0]=f2b(sa0.x); av[1]=f2b(sa0.y); av[2]=f2b(sa0.z); av[3]=f2b(sa0.w);
        av[4]=f2b(sa1.x); av[5]=f2b(sa1.y); av[6]=f2b(sa1.z); av[7]=f2b(sa1.w);
        *(short8*)&As[0][ar][ak] = av;
        #pragma unroll
        for (int p = 0; p < 4; ++p)
            *(short8*)&Bs[0][ar + p * 128][ak] = sb[p];
        if (arv) {
            *(float4*)&orow[0] = make_float4(0.4f*sa0.x, 0.4f*sa0.y, 0.4f*sa0.z, 0.4f*sa0.w);
            *(float4*)&orow[4] = make_float4(0.4f*sa1.x, 0.4f*sa1.y, 0.4f*sa1.z, 0.4f*sa1.w);
        }
    }
    LDS_BARRIER();

    for (int ks = 0; ks < 16; ++ks) {
        int cur = ks & 1;
        int kn = (ks + 1) * 32;
        // (1) issue next chunk's global loads early (vmcnt stays outstanding)
        if (kn < 512) {
            sa0 = *(const float4*)&xrow[kn];
            sa1 = *(const float4*)&xrow[kn + 4];
            #pragma unroll
            for (int p = 0; p < 4; ++p)
                sb[p] = *(const short8*)&brow[(size_t)p * 128 * CH + kn];
        }
        // (2) fragment reads + MFMA on current buffer
        short8 af[4], bfr[8];
        #pragma unroll
        for (int i = 0; i < 4; ++i)
            af[i] = *(const short8*)&As[cur][wm * 64 + i * 16 + fm][kq];
        #pragma unroll
        for (int j = 0; j < 8; ++j)
            bfr[j] = *(const short8*)&Bs[cur][wn * 128 + j * 16 + fm][kq];
        #pragma unroll
        for (int i = 0; i < 4; ++i)
            #pragma unroll
            for (int j = 0; j < 8; ++j)
                acc[i][j] = __builtin_amdgcn_mfma_f32_16x16x32_bf16(af[i], bfr[j], acc[i][j], 0, 0, 0);
        // (3) stage next chunk into the other buffer + fused out-store
        if (kn < 512) {
            short8 av;
            av[0]=f2b(sa0.x); av[1]=f2b(sa0.y); av[2]=f2b(sa0.z); av[3]=f2b(sa0.w);
            av[4]=f2b(sa1.x); av[5]=f2b(sa1.y); av[6]=f2b(sa1.z); av[7]=f2b(sa1.w);
            *(short8*)&As[cur ^ 1][ar][ak] = av;
            #pragma unroll
            for (int p = 0; p < 4; ++p)
                *(short8*)&Bs[cur ^ 1][ar + p * 128][ak] = sb[p];
            if (arv) {
                *(float4*)&orow[kn]     = make_float4(0.4f*sa0.x, 0.4f*sa0.y, 0.4f*sa0.z, 0.4f*sa0.w);
                *(float4*)&orow[kn + 4] = make_float4(0.4f*sa1.x, 0.4f*sa1.y, 0.4f*sa1.z, 0.4f*sa1.w);
            }
        }
        // (4) LDS-only barrier: out-stores & loads are NOT drained
        LDS_BARRIER();
    }

    // epilogue: Wbuf = acc + B0 (bf16)
    float b0e[8];
    #pragma unroll
    for (int j = 0; j < 8; ++j) b0e[j] = k0p[wn * 128 + j * 16 + fm];
    #pragma unroll
    for (int i = 0; i < 4; ++i)
        #pragma unroll
        for (int r = 0; r < 4; ++r) {
            int row = i0 + wm * 64 + i * 16 + fq * 4 + r;
            if (row < Mc) {
                #pragma unroll
                for (int j = 0; j < 8; ++j) {
                    int col = wn * 128 + j * 16 + fm;
                    Wbuf[(size_t)row * CH + col] = f2b(acc[i][j][r] + b0e[j]);
                }
            }
        }
}

// ---------------- fused speculative scan (R6 exact-rescan version) ----------------
__device__ __forceinline__ short8 wload(const unsigned short* Wbuf, int t, int a0, int b, int c0) {
    int r = t - 1 - a0; if (r < 0) r = 0;
    return *(const short8*)&Wbuf[((size_t)r * BATCH + b) * CH + c0];
}

__global__ __launch_bounds__(512) void scan_all(
    const unsigned short* __restrict__ Wbuf,
    const float* __restrict__ k0p,
    const float* __restrict__ vcin,
    float* __restrict__ vcout,
    int* __restrict__ flag,
    int t0, int a0, int segs, int chunk_idx)
{
    const float F = 1.1790184577738595e-3f;   // 0.9^64
    __shared__ float Ssh[8][CH];
    int b = blockIdx.x;
    int seg = threadIdx.x >> 6;
    int lane = threadIdx.x & 63;
    int c0 = lane * 8;
    bool active = seg < segs;
    int tstart = t0 + seg * 64;

    float B0[8];
    #pragma unroll
    for (int k = 0; k < 8; ++k) B0[k] = k0p[c0 + k];

    // ---- phase A: segment sums (zero-start end value) ----
    if (active) {
        float S[8] = {};
        short8 pz[4];
        #pragma unroll
        for (int p = 0; p < 4; ++p) pz[p] = wload(Wbuf, tstart + p, a0, b, c0);
        for (int ii = 0; ii < 64; ii += 4) {
            #pragma unroll
            for (int p = 0; p < 4; ++p) {
                int t = tstart + ii + p;
                short8 zv = pz[p];
                int tn = ii + p + 4;
                if (tn < 64) pz[p] = wload(Wbuf, tstart + tn, a0, b, c0);
                #pragma unroll
                for (int k = 0; k < 8; ++k) {
                    float wv = (t == 0) ? B0[k] : b2f((unsigned short)zv[k]);
                    S[k] = fmaf(0.9f, S[k], wv);
                }
            }
        }
        #pragma unroll
        for (int k = 0; k < 8; ++k) Ssh[seg][c0 + k] = S[k];
    }
    __syncthreads();

    // ---- phase B: exact v at my segment start ----
    float v[8];
    if (t0 == 0) {
        #pragma unroll
        for (int k = 0; k < 8; ++k) v[k] = 0.0f;
    } else {
        const float* vp = &vcin[(size_t)b * CH + c0];
        float4 v0 = *(const float4*)&vp[0], v1 = *(const float4*)&vp[4];
        v[0]=v0.x; v[1]=v0.y; v[2]=v0.z; v[3]=v0.w; v[4]=v1.x; v[5]=v1.y; v[6]=v1.z; v[7]=v1.w;
    }
    for (int u = 0; u < seg; ++u) {
        #pragma unroll
        for (int k = 0; k < 8; ++k) v[k] = fmaf(v[k], F, Ssh[u][c0 + k]);
    }

    // ---- phase C: exact rescan + threshold flag ----
    if (active) {
        bool anyhit = false;
        short8 pz[4];
        #pragma unroll
        for (int p = 0; p < 4; ++p) pz[p] = wload(Wbuf, tstart + p, a0, b, c0);
        for (int ii = 0; ii < 64; ii += 4) {
            #pragma unroll
            for (int p = 0; p < 4; ++p) {
                int t = tstart + ii + p;
                short8 zv = pz[p];
                int tn = ii + p + 4;
                if (tn < 64) pz[p] = wload(Wbuf, tstart + tn, a0, b, c0);
                float m = -1e30f;
                #pragma unroll
                for (int k = 0; k < 8; ++k) {
                    float wv = (t == 0) ? B0[k] : b2f((unsigned short)zv[k]);
                    v[k] = fmaf(0.9f, v[k], wv);
                    m = fmaxf(m, v[k]);
                }
                anyhit |= (m >= 0.995f);
            }
        }
        if (__ballot(anyhit) != 0ULL && lane == 0) atomicMin(flag, chunk_idx);
        if (seg == segs - 1) {
            float* vp = &vcout[(size_t)b * CH + c0];
            *(float4*)&vp[0] = make_float4(v[0], v[1], v[2], v[3]);
            *(float4*)&vp[4] = make_float4(v[4], v[5], v[6], v[7]);
        }
    }
}

// ---------------- exact sequential fallback (runs only if flag fired) ----------------
__global__ __launch_bounds__(64) void seq_fix(
    const float* __restrict__ x,
    const float* __restrict__ wt,
    const unsigned short* __restrict__ Wbuf,
    const float* __restrict__ isb,
    const float* __restrict__ k0p,
    const int* __restrict__ flag,
    const float* __restrict__ vcin,
    float* __restrict__ out,
    float* __restrict__ v_state,
    unsigned long long* __restrict__ s_state,
    int t0, int t1, int a0, int chunk_idx, int save_state)
{
    int fl = *flag;
    if (fl > chunk_idx) return;
    int b = blockIdx.x;
    int lane = threadIdx.x;
    int c0 = lane * 8;

    float is6[8], B0[8];
    #pragma unroll
    for (int k = 0; k < 8; ++k) {
        is6[k] = 0.06f * isb[c0 + k];
        B0[k]  = k0p[c0 + k];
    }

    float v[8];
    unsigned long long mk[8];
    if (t0 == 0) {
        #pragma unroll
        for (int k = 0; k < 8; ++k) v[k] = 0.0f;
        #pragma unroll
        for (int j = 0; j < 8; ++j) mk[j] = 0ULL;
    } else if (fl == chunk_idx) {
        #pragma unroll
        for (int k = 0; k < 8; ++k) v[k] = vcin[(size_t)b * CH + c0 + k];
        #pragma unroll
        for (int j = 0; j < 8; ++j) mk[j] = 0ULL;
    } else {
        #pragma unroll
        for (int k = 0; k < 8; ++k) v[k] = v_state[(size_t)b * CH + c0 + k];
        #pragma unroll
        for (int j = 0; j < 8; ++j) mk[j] = s_state[b * 8 + j];
    }

    float xc[8]; short8 wc;
    {
        const float4* xp = (const float4*)&x[((size_t)t0 * BATCH + b) * CH + c0];
        float4 x0 = xp[0], x1 = xp[1];
        xc[0]=x0.x; xc[1]=x0.y; xc[2]=x0.z; xc[3]=x0.w; xc[4]=x1.x; xc[5]=x1.y; xc[6]=x1.z; xc[7]=x1.w;
        wc = wload(Wbuf, t0, a0, b, c0);
    }
    for (int t = t0; t < t1; ++t) {
        float xn[8]; short8 wn_;
        if (t + 1 < t1) {
            const float4* xp = (const float4*)&x[((size_t)(t + 1) * BATCH + b) * CH + c0];
            float4 x0 = xp[0], x1 = xp[1];
            xn[0]=x0.x; xn[1]=x0.y; xn[2]=x0.z; xn[3]=x0.w; xn[4]=x1.x; xn[5]=x1.y; xn[6]=x1.z; xn[7]=x1.w;
            wn_ = wload(Wbuf, t + 1, a0, b, c0);
        }
        float acc[8] = {};
        unsigned long long anym = mk[0]|mk[1]|mk[2]|mk[3]|mk[4]|mk[5]|mk[6]|mk[7];
        if (anym) {
            #pragma unroll
            for (int j = 0; j < 8; ++j) {
                unsigned long long m = mk[j];
                while (m) {
                    int l = __builtin_ctzll(m); m &= m - 1;
                    const float4* wr = (const float4*)&wt[(size_t)(l * 8 + j) * CH + c0];
                    float4 w0 = wr[0], w1 = wr[1];
                    acc[0]+=w0.x; acc[1]+=w0.y; acc[2]+=w0.z; acc[3]+=w0.w;
                    acc[4]+=w1.x; acc[5]+=w1.y; acc[6]+=w1.z; acc[7]+=w1.w;
                }
            }
        }
        bool s[8];
        #pragma unroll
        for (int k = 0; k < 8; ++k) {
            float wv = (t == 0) ? B0[k] : b2f((unsigned short)wc[k]);
            float vv = fmaf(0.9f, v[k], fmaf(is6[k], acc[k], wv));
            s[k] = (vv >= 1.0f);
            v[k] = s[k] ? 0.0f : vv;
        }
        float4* op = (float4*)&out[((size_t)t * BATCH + b) * CH + c0];
        op[0] = make_float4(fmaf(0.4f,xc[0],s[0]?0.6f:0.f), fmaf(0.4f,xc[1],s[1]?0.6f:0.f),
                            fmaf(0.4f,xc[2],s[2]?0.6f:0.f), fmaf(0.4f,xc[3],s[3]?0.6f:0.f));
        op[1] = make_float4(fmaf(0.4f,xc[4],s[4]?0.6f:0.f), fmaf(0.4f,xc[5],s[5]?0.6f:0.f),
                            fmaf(0.4f,xc[6],s[6]?0.6f:0.f), fmaf(0.4f,xc[7],s[7]?0.6f:0.f));
        #pragma unroll
        for (int j = 0; j < 8; ++j) mk[j] = __ballot(s[j]);
        #pragma unroll
        for (int k = 0; k < 8; ++k) xc[k] = xn[k];
        wc = wn_;
    }
    if (save_state) {
        #pragma unroll
        for (int k = 0; k < 8; ++k) v_state[(size_t)b * CH + c0 + k] = v[k];
        if (lane < 8) s_state[b * 8 + lane] = mk[lane];
    }
}

extern "C" void kernel_launch(void* const* d_in, const int* in_sizes, int n_in,
                              void* d_out, int out_size, void* d_ws, size_t ws_size,
                              hipStream_t stream) {
    const float* x     = (const float*)d_in[0];
    const float* cw    = (const float*)d_in[1];
    const float* cb    = (const float*)d_in[2];
    const float* gamma = (const float*)d_in[3];
    const float* beta  = (const float*)d_in[4];
    const float* mean  = (const float*)d_in[5];
    const float* var   = (const float*)d_in[6];
    float* out = (float*)d_out;

    char* ws = (char*)d_ws;
    size_t off = 0;
    auto alloc = [&](size_t bytes) -> char* {
        char* p = ws + off;
        off = (off + bytes + 255) & ~(size_t)255;
        return p;
    };
    unsigned short* wb = (unsigned short*)alloc((size_t)CH * CH * 2);
    float* wt  = (float*)alloc((size_t)CH * CH * 4);
    float* isb = (float*)alloc(CH * 4);
    float* k0p = (float*)alloc(CH * 4);
    int* flag  = (int*)alloc(256);
    float* vst = (float*)alloc((size_t)BATCH * CH * 4);
    unsigned long long* sst = (unsigned long long*)alloc(BATCH * 8 * 8);
    float* vca = (float*)alloc((size_t)BATCH * CH * 4);
    float* vcb = (float*)alloc((size_t)BATCH * CH * 4);
    unsigned short* Wbuf = (unsigned short*)(ws + off);

    size_t avail = (ws_size > off) ? ws_size - off : 0;
    long rows = (long)(avail / ((size_t)BATCH * CH * 2));
    long cs = ((rows - 1) / 64) * 64;
    if (cs > T_STEPS) cs = T_STEPS;
    if (cs < 64) cs = 64;
    int CS = (int)cs;

    hipLaunchKernelGGL(prep, dim3((CH * CH + 255) / 256), dim3(256), 0, stream,
                       cw, cb, gamma, beta, mean, var, wb, wt, isb, k0p, flag);

    float *vin = vca, *vout = vcb;
    int k = 0;
    for (int t0 = 0; t0 < T_STEPS; t0 += CS, ++k) {
        int t1 = t0 + CS; if (t1 > T_STEPS) t1 = T_STEPS;
        int a0 = (t0 == 0) ? 0 : t0 - 1;
        int gend = (t1 == T_STEPS) ? T_STEPS : t1 - 1;
        int Mc = (gend - a0) * BATCH;
        hipLaunchKernelGGL(gemm_fused, dim3((Mc + GBM - 1) / GBM), dim3(512), 0, stream,
                           x + (size_t)a0 * BATCH * CH, wb, k0p, Wbuf,
                           out + (size_t)a0 * BATCH * CH, Mc);
        int segs = (t1 - t0) / 64;
        hipLaunchKernelGGL(scan_all, dim3(BATCH), dim3(512), 0, stream,
                           Wbuf, k0p, vin, vout, flag, t0, a0, segs, k);
        hipLaunchKernelGGL(seq_fix, dim3(BATCH), dim3(64), 0, stream,
                           x, wt, Wbuf, isb, k0p, flag, vin, out, vst, sst,
                           t0, t1, a0, k, (t1 < T_STEPS) ? 1 : 0);
        float* tmp = vin; vin = vout; vout = tmp;
    }
}

// Round 9
// 65.694 us; speedup vs baseline: 4.2122x; 1.1764x over previous
//
#include <hip/hip_runtime.h>
#include <hip/hip_bf16.h>
#include <stdint.h>

#define T_STEPS 512
#define BATCH 64
#define CH 512

using short8 = __attribute__((ext_vector_type(8))) short;
using f32x4  = __attribute__((ext_vector_type(4))) float;

__device__ __forceinline__ unsigned short f2b(float f) {
    union { __hip_bfloat16 h; unsigned short u; } c;
    c.h = __float2bfloat16(f);
    return c.u;
}
__device__ __forceinline__ float b2f(unsigned short h) {
    union { unsigned u; float f; } c; c.u = ((unsigned)h) << 16;
    return c.f;
}

// LDS-only barrier (no vmcnt drain); rule-18 fencing
#define LDS_BARRIER() do {                                   \
    __builtin_amdgcn_sched_barrier(0);                       \
    asm volatile("s_waitcnt lgkmcnt(0)" ::: "memory");       \
    __builtin_amdgcn_s_barrier();                            \
    __builtin_amdgcn_sched_barrier(0);                       \
} while (0)

// ---------------- prep ----------------
__global__ void prep(const float* __restrict__ cw, const float* __restrict__ cb,
                     const float* __restrict__ gamma, const float* __restrict__ beta,
                     const float* __restrict__ mean, const float* __restrict__ var,
                     unsigned short* __restrict__ wb,   // [d][c] bf16, pre-scaled 0.04*is_d
                     float* __restrict__ wt,            // [c][d] fp32 raw w1
                     float* __restrict__ isb,
                     float* __restrict__ k0p,           // B0_d
                     int* __restrict__ flag) {
    int idx = blockIdx.x * 256 + threadIdx.x;
    if (idx == 0) *flag = 0x7fffffff;
    if (idx >= CH * CH) return;
    int d = idx >> 9, c = idx & 511;
    float is = gamma[d] * rsqrtf(var[d] + 1e-5f);
    float w = cw[((size_t)d * CH + c) * 3 + 1];
    wb[idx] = f2b(0.04f * is * w);
    wt[(size_t)c * CH + d] = w;
    if (c == 0) {
        isb[d] = is;
        k0p[d] = 0.1f * ((cb[d] - mean[d]) * is + beta[d]);
    }
}

// ---------------- fused GEMM: BM=128, BN=512, BK=32, 1-step-ahead staging ----------------
#define GBM 128
#define PADK 40

__global__ __launch_bounds__(512, 2) void gemm_fused(
    const float* __restrict__ Xp,
    const unsigned short* __restrict__ wbp,
    const float* __restrict__ k0p,
    unsigned short* __restrict__ Wbuf,     // [Mc][512] bf16
    float* __restrict__ outp,
    int Mc)
{
    __shared__ __align__(16) unsigned short As[2][GBM][PADK];
    __shared__ __align__(16) unsigned short Bs[2][512][PADK];
    int tid = threadIdx.x;
    int lane = tid & 63, wid = tid >> 6;
    int wm = wid >> 2, wn = wid & 3;       // 2x4 waves, 64x128 tile each
    int i0 = blockIdx.x * GBM;
    int fm = lane & 15, fq = lane >> 4;
    int kq = fq * 8;

    int ar = tid >> 2;                 // A/B row 0..127
    int ak = (tid & 3) * 8;            // k-offset: 0,8,16,24

    int grow = i0 + ar;
    bool arv = grow < Mc;
    int growc = arv ? grow : (Mc - 1);
    const float* xrow = &Xp[(size_t)growc * CH + ak];
    float* orow = &outp[(size_t)grow * CH + ak];
    const unsigned short* brow = &wbp[(size_t)ar * CH + ak];

    f32x4 acc[4][8] = {};

    // two alternating staging sets: chunk c lives in set[c&1]
    float4 sa0[2], sa1[2];
    short8 sb[2][4];

    // ---- prologue: load chunk0 -> write buf0 + out-store; issue chunk1 ----
    {
        sa0[0] = *(const float4*)&xrow[0];
        sa1[0] = *(const float4*)&xrow[4];
        #pragma unroll
        for (int p = 0; p < 4; ++p)
            sb[0][p] = *(const short8*)&brow[(size_t)p * 128 * CH];
        short8 av;
        av[0]=f2b(sa0[0].x); av[1]=f2b(sa0[0].y); av[2]=f2b(sa0[0].z); av[3]=f2b(sa0[0].w);
        av[4]=f2b(sa1[0].x); av[5]=f2b(sa1[0].y); av[6]=f2b(sa1[0].z); av[7]=f2b(sa1[0].w);
        *(short8*)&As[0][ar][ak] = av;
        #pragma unroll
        for (int p = 0; p < 4; ++p)
            *(short8*)&Bs[0][ar + p * 128][ak] = sb[0][p];
        if (arv) {
            *(float4*)&orow[0] = make_float4(0.4f*sa0[0].x, 0.4f*sa0[0].y, 0.4f*sa0[0].z, 0.4f*sa0[0].w);
            *(float4*)&orow[4] = make_float4(0.4f*sa1[0].x, 0.4f*sa1[0].y, 0.4f*sa1[0].z, 0.4f*sa1[0].w);
        }
        // issue chunk 1 into set 1 (consumed next iteration -> full-step cover)
        sa0[1] = *(const float4*)&xrow[32];
        sa1[1] = *(const float4*)&xrow[36];
        #pragma unroll
        for (int p = 0; p < 4; ++p)
            sb[1][p] = *(const short8*)&brow[(size_t)p * 128 * CH + 32];
    }
    LDS_BARRIER();

    for (int ks = 0; ks < 16; ++ks) {
        int cur = ks & 1;
        int kw = ks + 1;                   // chunk to write this step (loaded last step)
        int ki = ks + 2;                   // chunk to issue this step
        if (kw < 16) {
            int sw = kw & 1;
            short8 av;
            av[0]=f2b(sa0[sw].x); av[1]=f2b(sa0[sw].y); av[2]=f2b(sa0[sw].z); av[3]=f2b(sa0[sw].w);
            av[4]=f2b(sa1[sw].x); av[5]=f2b(sa1[sw].y); av[6]=f2b(sa1[sw].z); av[7]=f2b(sa1[sw].w);
            *(short8*)&As[cur ^ 1][ar][ak] = av;
            #pragma unroll
            for (int p = 0; p < 4; ++p)
                *(short8*)&Bs[cur ^ 1][ar + p * 128][ak] = sb[sw][p];
            if (arv) {
                *(float4*)&orow[kw * 32]     = make_float4(0.4f*sa0[sw].x, 0.4f*sa0[sw].y, 0.4f*sa0[sw].z, 0.4f*sa0[sw].w);
                *(float4*)&orow[kw * 32 + 4] = make_float4(0.4f*sa1[sw].x, 0.4f*sa1[sw].y, 0.4f*sa1[sw].z, 0.4f*sa1[sw].w);
            }
        }
        if (ki < 16) {
            int si = ki & 1;
            sa0[si] = *(const float4*)&xrow[ki * 32];
            sa1[si] = *(const float4*)&xrow[ki * 32 + 4];
            #pragma unroll
            for (int p = 0; p < 4; ++p)
                sb[si][p] = *(const short8*)&brow[(size_t)p * 128 * CH + ki * 32];
        }
        // MFMA on buf[cur], bfr in two 4-groups to cap register pressure
        short8 af[4];
        #pragma unroll
        for (int i = 0; i < 4; ++i)
            af[i] = *(const short8*)&As[cur][wm * 64 + i * 16 + fm][kq];
        #pragma unroll
        for (int jh = 0; jh < 2; ++jh) {
            short8 bfr[4];
            #pragma unroll
            for (int j = 0; j < 4; ++j)
                bfr[j] = *(const short8*)&Bs[cur][wn * 128 + (jh * 4 + j) * 16 + fm][kq];
            #pragma unroll
            for (int i = 0; i < 4; ++i)
                #pragma unroll
                for (int j = 0; j < 4; ++j)
                    acc[i][jh * 4 + j] = __builtin_amdgcn_mfma_f32_16x16x32_bf16(af[i], bfr[j], acc[i][jh * 4 + j], 0, 0, 0);
        }
        LDS_BARRIER();
    }

    // epilogue: Wbuf = acc + B0 (bf16)
    float b0e[8];
    #pragma unroll
    for (int j = 0; j < 8; ++j) b0e[j] = k0p[wn * 128 + j * 16 + fm];
    #pragma unroll
    for (int i = 0; i < 4; ++i)
        #pragma unroll
        for (int r = 0; r < 4; ++r) {
            int row = i0 + wm * 64 + i * 16 + fq * 4 + r;
            if (row < Mc) {
                #pragma unroll
                for (int j = 0; j < 8; ++j) {
                    int col = wn * 128 + j * 16 + fm;
                    Wbuf[(size_t)row * CH + col] = f2b(acc[i][j][r] + b0e[j]);
                }
            }
        }
}

// ---------------- speculative scan: 512-block passes ----------------
__device__ __forceinline__ short8 wload(const unsigned short* Wbuf, int t, int a0, int b, int c0) {
    int r = t - 1 - a0; if (r < 0) r = 0;
    return *(const short8*)&Wbuf[((size_t)r * BATCH + b) * CH + c0];
}

// pass A: per-(b,seg) zero-start segment end value S
__global__ __launch_bounds__(64) void scan_a(
    const unsigned short* __restrict__ Wbuf,
    const float* __restrict__ k0p,
    float* __restrict__ Sbuf,        // [B][segs][CH]
    int t0, int a0, int segs)
{
    int b = blockIdx.x & (BATCH - 1);
    int seg = blockIdx.x >> 6;
    int lane = threadIdx.x, c0 = lane * 8;
    int tstart = t0 + seg * 64;

    float B0[8];
    #pragma unroll
    for (int k = 0; k < 8; ++k) B0[k] = k0p[c0 + k];

    float S[8] = {};
    short8 pz[8];
    #pragma unroll
    for (int p = 0; p < 8; ++p) pz[p] = wload(Wbuf, tstart + p, a0, b, c0);

    for (int ii = 0; ii < 64; ii += 8) {
        #pragma unroll
        for (int p = 0; p < 8; ++p) {
            int t = tstart + ii + p;
            short8 zv = pz[p];
            int tn = ii + p + 8;
            if (tn < 64) pz[p] = wload(Wbuf, tstart + tn, a0, b, c0);
            #pragma unroll
            for (int k = 0; k < 8; ++k) {
                float wv = (t == 0) ? B0[k] : b2f((unsigned short)zv[k]);
                S[k] = fmaf(0.9f, S[k], wv);
            }
        }
    }
    float* sp = &Sbuf[((size_t)b * segs + seg) * CH + c0];
    *(float4*)&sp[0] = make_float4(S[0], S[1], S[2], S[3]);
    *(float4*)&sp[4] = make_float4(S[4], S[5], S[6], S[7]);
}

// pass C: per-(b,seg) exact prefix + exact rescan + flag (+carry at last seg)
__global__ __launch_bounds__(64) void scan_c(
    const unsigned short* __restrict__ Wbuf,
    const float* __restrict__ k0p,
    const float* __restrict__ Sbuf,
    const float* __restrict__ vcin,
    float* __restrict__ vcout,
    int* __restrict__ flag,
    int t0, int a0, int segs, int chunk_idx)
{
    const float F = 1.1790184577738595e-3f;   // 0.9^64
    int b = blockIdx.x & (BATCH - 1);
    int seg = blockIdx.x >> 6;
    int lane = threadIdx.x, c0 = lane * 8;
    int tstart = t0 + seg * 64;

    float B0[8];
    #pragma unroll
    for (int k = 0; k < 8; ++k) B0[k] = k0p[c0 + k];

    float v[8];
    if (t0 == 0) {
        #pragma unroll
        for (int k = 0; k < 8; ++k) v[k] = 0.0f;
    } else {
        const float* vp = &vcin[(size_t)b * CH + c0];
        float4 v0 = *(const float4*)&vp[0], v1 = *(const float4*)&vp[4];
        v[0]=v0.x; v[1]=v0.y; v[2]=v0.z; v[3]=v0.w; v[4]=v1.x; v[5]=v1.y; v[6]=v1.z; v[7]=v1.w;
    }
    for (int u = 0; u < seg; ++u) {
        const float* sp = &Sbuf[((size_t)b * segs + u) * CH + c0];
        float4 s0 = *(const float4*)&sp[0], s1 = *(const float4*)&sp[4];
        float sv[8] = {s0.x, s0.y, s0.z, s0.w, s1.x, s1.y, s1.z, s1.w};
        #pragma unroll
        for (int k = 0; k < 8; ++k) v[k] = fmaf(v[k], F, sv[k]);
    }

    bool anyhit = false;
    short8 pz[8];
    #pragma unroll
    for (int p = 0; p < 8; ++p) pz[p] = wload(Wbuf, tstart + p, a0, b, c0);

    for (int ii = 0; ii < 64; ii += 8) {
        #pragma unroll
        for (int p = 0; p < 8; ++p) {
            int t = tstart + ii + p;
            short8 zv = pz[p];
            int tn = ii + p + 8;
            if (tn < 64) pz[p] = wload(Wbuf, tstart + tn, a0, b, c0);
            float m = -1e30f;
            #pragma unroll
            for (int k = 0; k < 8; ++k) {
                float wv = (t == 0) ? B0[k] : b2f((unsigned short)zv[k]);
                v[k] = fmaf(0.9f, v[k], wv);
                m = fmaxf(m, v[k]);
            }
            anyhit |= (m >= 0.995f);
        }
    }
    if (__ballot(anyhit) != 0ULL && lane == 0) atomicMin(flag, chunk_idx);
    if (seg == segs - 1) {
        float* vp = &vcout[(size_t)b * CH + c0];
        *(float4*)&vp[0] = make_float4(v[0], v[1], v[2], v[3]);
        *(float4*)&vp[4] = make_float4(v[4], v[5], v[6], v[7]);
    }
}

// ---------------- exact sequential fallback (runs only if flag fired) ----------------
__global__ __launch_bounds__(64) void seq_fix(
    const float* __restrict__ x,
    const float* __restrict__ wt,
    const unsigned short* __restrict__ Wbuf,
    const float* __restrict__ isb,
    const float* __restrict__ k0p,
    const int* __restrict__ flag,
    const float* __restrict__ vcin,
    float* __restrict__ out,
    float* __restrict__ v_state,
    unsigned long long* __restrict__ s_state,
    int t0, int t1, int a0, int chunk_idx, int save_state)
{
    int fl = *flag;
    if (fl > chunk_idx) return;
    int b = blockIdx.x;
    int lane = threadIdx.x;
    int c0 = lane * 8;

    float is6[8], B0[8];
    #pragma unroll
    for (int k = 0; k < 8; ++k) {
        is6[k] = 0.06f * isb[c0 + k];
        B0[k]  = k0p[c0 + k];
    }

    float v[8];
    unsigned long long mk[8];
    if (t0 == 0) {
        #pragma unroll
        for (int k = 0; k < 8; ++k) v[k] = 0.0f;
        #pragma unroll
        for (int j = 0; j < 8; ++j) mk[j] = 0ULL;
    } else if (fl == chunk_idx) {
        #pragma unroll
        for (int k = 0; k < 8; ++k) v[k] = vcin[(size_t)b * CH + c0 + k];
        #pragma unroll
        for (int j = 0; j < 8; ++j) mk[j] = 0ULL;
    } else {
        #pragma unroll
        for (int k = 0; k < 8; ++k) v[k] = v_state[(size_t)b * CH + c0 + k];
        #pragma unroll
        for (int j = 0; j < 8; ++j) mk[j] = s_state[b * 8 + j];
    }

    float xc[8]; short8 wc;
    {
        const float4* xp = (const float4*)&x[((size_t)t0 * BATCH + b) * CH + c0];
        float4 x0 = xp[0], x1 = xp[1];
        xc[0]=x0.x; xc[1]=x0.y; xc[2]=x0.z; xc[3]=x0.w; xc[4]=x1.x; xc[5]=x1.y; xc[6]=x1.z; xc[7]=x1.w;
        wc = wload(Wbuf, t0, a0, b, c0);
    }
    for (int t = t0; t < t1; ++t) {
        float xn[8]; short8 wn_;
        if (t + 1 < t1) {
            const float4* xp = (const float4*)&x[((size_t)(t + 1) * BATCH + b) * CH + c0];
            float4 x0 = xp[0], x1 = xp[1];
            xn[0]=x0.x; xn[1]=x0.y; xn[2]=x0.z; xn[3]=x0.w; xn[4]=x1.x; xn[5]=x1.y; xn[6]=x1.z; xn[7]=x1.w;
            wn_ = wload(Wbuf, t + 1, a0, b, c0);
        }
        float acc[8] = {};
        unsigned long long anym = mk[0]|mk[1]|mk[2]|mk[3]|mk[4]|mk[5]|mk[6]|mk[7];
        if (anym) {
            #pragma unroll
            for (int j = 0; j < 8; ++j) {
                unsigned long long m = mk[j];
                while (m) {
                    int l = __builtin_ctzll(m); m &= m - 1;
                    const float4* wr = (const float4*)&wt[(size_t)(l * 8 + j) * CH + c0];
                    float4 w0 = wr[0], w1 = wr[1];
                    acc[0]+=w0.x; acc[1]+=w0.y; acc[2]+=w0.z; acc[3]+=w0.w;
                    acc[4]+=w1.x; acc[5]+=w1.y; acc[6]+=w1.z; acc[7]+=w1.w;
                }
            }
        }
        bool s[8];
        #pragma unroll
        for (int k = 0; k < 8; ++k) {
            float wv = (t == 0) ? B0[k] : b2f((unsigned short)wc[k]);
            float vv = fmaf(0.9f, v[k], fmaf(is6[k], acc[k], wv));
            s[k] = (vv >= 1.0f);
            v[k] = s[k] ? 0.0f : vv;
        }
        float4* op = (float4*)&out[((size_t)t * BATCH + b) * CH + c0];
        op[0] = make_float4(fmaf(0.4f,xc[0],s[0]?0.6f:0.f), fmaf(0.4f,xc[1],s[1]?0.6f:0.f),
                            fmaf(0.4f,xc[2],s[2]?0.6f:0.f), fmaf(0.4f,xc[3],s[3]?0.6f:0.f));
        op[1] = make_float4(fmaf(0.4f,xc[4],s[4]?0.6f:0.f), fmaf(0.4f,xc[5],s[5]?0.6f:0.f),
                            fmaf(0.4f,xc[6],s[6]?0.6f:0.f), fmaf(0.4f,xc[7],s[7]?0.6f:0.f));
        #pragma unroll
        for (int j = 0; j < 8; ++j) mk[j] = __ballot(s[j]);
        #pragma unroll
        for (int k = 0; k < 8; ++k) xc[k] = xn[k];
        wc = wn_;
    }
    if (save_state) {
        #pragma unroll
        for (int k = 0; k < 8; ++k) v_state[(size_t)b * CH + c0 + k] = v[k];
        if (lane < 8) s_state[b * 8 + lane] = mk[lane];
    }
}

extern "C" void kernel_launch(void* const* d_in, const int* in_sizes, int n_in,
                              void* d_out, int out_size, void* d_ws, size_t ws_size,
                              hipStream_t stream) {
    const float* x     = (const float*)d_in[0];
    const float* cw    = (const float*)d_in[1];
    const float* cb    = (const float*)d_in[2];
    const float* gamma = (const float*)d_in[3];
    const float* beta  = (const float*)d_in[4];
    const float* mean  = (const float*)d_in[5];
    const float* var   = (const float*)d_in[6];
    float* out = (float*)d_out;

    char* ws = (char*)d_ws;
    size_t off = 0;
    auto alloc = [&](size_t bytes) -> char* {
        char* p = ws + off;
        off = (off + bytes + 255) & ~(size_t)255;
        return p;
    };
    unsigned short* wb = (unsigned short*)alloc((size_t)CH * CH * 2);
    float* wt  = (float*)alloc((size_t)CH * CH * 4);
    float* isb = (float*)alloc(CH * 4);
    float* k0p = (float*)alloc(CH * 4);
    int* flag  = (int*)alloc(256);
    float* vst = (float*)alloc((size_t)BATCH * CH * 4);
    unsigned long long* sst = (unsigned long long*)alloc(BATCH * 8 * 8);
    float* vca = (float*)alloc((size_t)BATCH * CH * 4);
    float* vcb = (float*)alloc((size_t)BATCH * CH * 4);
    float* Sb  = (float*)alloc((size_t)BATCH * 8 * CH * 4);
    unsigned short* Wbuf = (unsigned short*)(ws + off);

    size_t avail = (ws_size > off) ? ws_size - off : 0;
    long rows = (long)(avail / ((size_t)BATCH * CH * 2));
    long cs = ((rows - 1) / 64) * 64;
    if (cs > T_STEPS) cs = T_STEPS;
    if (cs < 64) cs = 64;
    int CS = (int)cs;

    hipLaunchKernelGGL(prep, dim3((CH * CH + 255) / 256), dim3(256), 0, stream,
                       cw, cb, gamma, beta, mean, var, wb, wt, isb, k0p, flag);

    float *vin = vca, *vout = vcb;
    int k = 0;
    for (int t0 = 0; t0 < T_STEPS; t0 += CS, ++k) {
        int t1 = t0 + CS; if (t1 > T_STEPS) t1 = T_STEPS;
        int a0 = (t0 == 0) ? 0 : t0 - 1;
        int gend = (t1 == T_STEPS) ? T_STEPS : t1 - 1;
        int Mc = (gend - a0) * BATCH;
        hipLaunchKernelGGL(gemm_fused, dim3((Mc + GBM - 1) / GBM), dim3(512), 0, stream,
                           x + (size_t)a0 * BATCH * CH, wb, k0p, Wbuf,
                           out + (size_t)a0 * BATCH * CH, Mc);
        int segs = (t1 - t0) / 64;
        hipLaunchKernelGGL(scan_a, dim3(BATCH * segs), dim3(64), 0, stream,
                           Wbuf, k0p, Sb, t0, a0, segs);
        hipLaunchKernelGGL(scan_c, dim3(BATCH * segs), dim3(64), 0, stream,
                           Wbuf, k0p, Sb, vin, vout, flag, t0, a0, segs, k);
        hipLaunchKernelGGL(seq_fix, dim3(BATCH), dim3(64), 0, stream,
                           x, wt, Wbuf, isb, k0p, flag, vin, out, vst, sst,
                           t0, t1, a0, k, (t1 < T_STEPS) ? 1 : 0);
        float* tmp = vin; vin = vout; vout = tmp;
    }
}